// Round 1
// baseline (1118.533 us; speedup 1.0000x reference)
//
#include <hip/hip_runtime.h>
#include <stdint.h>

#define NB 64
#define NL 20
#define ND 2304
#define NE 4
#define NH 4608
#define NM 1280   // B*L

typedef float f32x4 __attribute__((ext_vector_type(4)));
typedef __bf16 bf16x8 __attribute__((ext_vector_type(8)));
typedef unsigned short u16;
typedef u16 u16x4 __attribute__((ext_vector_type(4)));
typedef unsigned int u32;
typedef u32 u32x4 __attribute__((ext_vector_type(4)));

__device__ __forceinline__ u16 f2bf(float f) {
  u32 u = __builtin_bit_cast(u32, f);
  u += 0x7fffu + ((u >> 16) & 1u);
  return (u16)(u >> 16);
}

// ---- ws layout (float offsets) ----
#define OFF_XFACC 0
#define OFF_XF    147456
#define OFF_H     294912
#define OFF_Y     1179648
#define OFF_AUX   1622016
#define OFF_CNT   1622020
#define OFF_ROWS  1622032
#define OFF_OFB   1622240
#define OFF_H1B   3096800
#define OFF_ENCWB 4571360
#define OFF_DECWB 7225568

__global__ __launch_bounds__(256) void k_zero(float* __restrict__ p) {
  p[(size_t)blockIdx.x * 256 + threadIdx.x] = 0.f;
}

// Fused conv1(3x3x3,pad1,relu) + conv2 d-slice partial, per (d,b) block.
__global__ __launch_bounds__(256) void k_conv(
    const float* __restrict__ in, const float* __restrict__ w1,
    const float* __restrict__ b1, const float* __restrict__ w2,
    float* __restrict__ xf_acc) {
  __shared__ float insl[3][50][50];
  __shared__ float c1[2][50][50];
  __shared__ float w1s[270];
  __shared__ float w2s[90];
  __shared__ float b1s[10];
  const int d = blockIdx.x, b = blockIdx.y, t = threadIdx.x;
  for (int i = t; i < 270; i += 256) w1s[i] = w1[i];
  for (int i = t; i < 90; i += 256) w2s[i] = w2[(size_t)((i / 9) * 20 + d) * 9 + (i % 9)];
  if (t < 10) b1s[t] = b1[t];
  for (int i = t; i < 7500; i += 256) {
    int s = i / 2500, rr = (i % 2500) / 50, cc = i % 50;
    int gd = d - 1 + s, gy = rr - 1, gx = cc - 1;
    float v = 0.f;
    if (gd >= 0 && gd < NL && (unsigned)gy < 48u && (unsigned)gx < 48u)
      v = in[((size_t)b * NL + gd) * ND + gy * 48 + gx];
    insl[s][rr][cc] = v;
  }
  for (int i = t; i < 5000; i += 256) ((float*)c1)[i] = 0.f;
  float s2[3][4];
#pragma unroll
  for (int qi = 0; qi < 3; ++qi)
#pragma unroll
    for (int xq = 0; xq < 4; ++xq) s2[qi][xq] = 0.f;
  __syncthreads();
  for (int pc = 0; pc < 5; ++pc) {
    // conv1 for channels 2pc, 2pc+1 (interior only; border stays 0 = conv2 padding)
#pragma unroll
    for (int qi = 0; qi < 3; ++qi) {
      int q = t + qi * 256;
      if (q < 576) {
        int y = q / 12, x0 = (q % 12) * 4;
        float a0[4], a1[4];
        const float bb0 = b1s[2 * pc], bb1 = b1s[2 * pc + 1];
#pragma unroll
        for (int xq = 0; xq < 4; ++xq) { a0[xq] = bb0; a1[xq] = bb1; }
#pragma unroll
        for (int kd = 0; kd < 3; ++kd)
#pragma unroll
          for (int ky = 0; ky < 3; ++ky) {
            float v[6];
#pragma unroll
            for (int i = 0; i < 6; ++i) v[i] = insl[kd][y + ky][x0 + i];
            const float* wa = &w1s[(2 * pc) * 27 + kd * 9 + ky * 3];
            const float* wb = wa + 27;
#pragma unroll
            for (int xq = 0; xq < 4; ++xq) {
              a0[xq] += v[xq] * wa[0] + v[xq + 1] * wa[1] + v[xq + 2] * wa[2];
              a1[xq] += v[xq] * wb[0] + v[xq + 1] * wb[1] + v[xq + 2] * wb[2];
            }
          }
#pragma unroll
        for (int xq = 0; xq < 4; ++xq) {
          c1[0][y + 1][x0 + 1 + xq] = fmaxf(a0[xq], 0.f);
          c1[1][y + 1][x0 + 1 + xq] = fmaxf(a1[xq], 0.f);
        }
      }
    }
    __syncthreads();
    // conv2 partial over these two channels
#pragma unroll
    for (int qi = 0; qi < 3; ++qi) {
      int q = t + qi * 256;
      if (q < 576) {
        int y = q / 12, x0 = (q % 12) * 4;
#pragma unroll
        for (int cc = 0; cc < 2; ++cc) {
#pragma unroll
          for (int ky = 0; ky < 3; ++ky) {
            float v[6];
#pragma unroll
            for (int i = 0; i < 6; ++i) v[i] = c1[cc][y + ky][x0 + i];
            const float* wr = &w2s[(2 * pc + cc) * 9 + ky * 3];
#pragma unroll
            for (int xq = 0; xq < 4; ++xq)
              s2[qi][xq] += v[xq] * wr[0] + v[xq + 1] * wr[1] + v[xq + 2] * wr[2];
          }
        }
      }
    }
    __syncthreads();
  }
#pragma unroll
  for (int qi = 0; qi < 3; ++qi) {
    int q = t + qi * 256;
    if (q < 576) {
#pragma unroll
      for (int xq = 0; xq < 4; ++xq)
        atomicAdd(&xf_acc[(size_t)b * ND + q * 4 + xq], s2[qi][xq]);
    }
  }
}

__global__ __launch_bounds__(256) void k_bias_relu(
    const float* __restrict__ acc, const float* __restrict__ c2b, float* __restrict__ xf) {
  size_t i = (size_t)blockIdx.x * 256 + threadIdx.x;
  xf[i] = fmaxf(acc[i] + c2b[0], 0.f);
}

// Gating: logits, argmax (top-1, gate=1.0), counts, row compaction, aux loss.
__global__ __launch_bounds__(256) void k_gate(
    const float* __restrict__ xf,
    const float* __restrict__ g0, const float* __restrict__ g1, const float* __restrict__ g2,
    float* __restrict__ aux, int* __restrict__ cnt, int* __restrict__ rows) {
  const int p = blockIdx.x, t = threadIdx.x;
  const float* __restrict__ g = (p == 0) ? g0 : ((p == 1) ? g1 : g2);
  __shared__ float lg[64][4];
  __shared__ int lidx[64];
  __shared__ int lcnt[4];
  if (t < 4) lcnt[t] = 0;
  const int wv = t >> 6, l = t & 63;
  for (int b0 = 0; b0 < 64; b0 += 4) {
    int bb = b0 + wv;
    f32x4 acc = {0.f, 0.f, 0.f, 0.f};
    const float* xr = xf + (size_t)bb * ND + l * 36;
    const float* gr = g + (size_t)l * 36 * 4;
#pragma unroll
    for (int i4 = 0; i4 < 9; ++i4) {
      f32x4 xv = *(const f32x4*)(xr + i4 * 4);
#pragma unroll
      for (int qq = 0; qq < 4; ++qq) {
        f32x4 gv = *(const f32x4*)(gr + (i4 * 4 + qq) * 4);
        acc += xv[qq] * gv;
      }
    }
#pragma unroll
    for (int e = 0; e < 4; ++e) {
      float pv = acc[e];
#pragma unroll
      for (int off = 32; off > 0; off >>= 1) pv += __shfl_down(pv, off);
      if (l == 0) lg[bb][e] = pv;
    }
  }
  __syncthreads();
  if (t < 64) {
    float best = lg[t][0];
    int bi = 0;
#pragma unroll
    for (int e = 1; e < 4; ++e)
      if (lg[t][e] > best) { best = lg[t][e]; bi = e; }
    lidx[t] = bi;
    atomicAdd(&lcnt[bi], 1);
  }
  __syncthreads();
  if (t == 0) {
    int ofs[4]; int run = 0;
#pragma unroll
    for (int e = 0; e < 4; ++e) { ofs[e] = run; run += lcnt[e]; cnt[p * 4 + e] = lcnt[e]; }
    for (int b = 0; b < 64; ++b) { int e = lidx[b]; rows[p * 64 + ofs[e]++] = b; }
    float var = 0.f;
#pragma unroll
    for (int e = 0; e < 4; ++e) { float dd = (float)lcnt[e] - 16.f; var += dd * dd; }
    var *= (1.f / 3.f);
    aux[p] = 0.02f * var / (256.f + 1e-10f);
  }
}

// MoE phase A: H[rowpos][j] = relu(x[row] @ w1[e] + b1[e]); weight-streaming, 32-row chunk.
__global__ __launch_bounds__(256) void k_moe1(
    const float* __restrict__ xf,
    const float* __restrict__ w1t, const float* __restrict__ w1a, const float* __restrict__ w1q,
    const float* __restrict__ b1t, const float* __restrict__ b1a, const float* __restrict__ b1q,
    const int* __restrict__ cnt, const int* __restrict__ rows, float* __restrict__ H) {
  const int tile = blockIdx.x;                 // 36 tiles x 128 cols = 4608
  const int pe = blockIdx.y >> 1, g = blockIdx.y & 1;
  const int p = pe >> 2, e = pe & 3;
  const int c = cnt[p * 4 + e];
  const int rstart = g * 32;
  if (rstart >= c) return;
  const int nrows = min(32, c - rstart);
  int pref = 0;
  for (int e2 = 0; e2 < e; ++e2) pref += cnt[p * 4 + e2];
  const float* __restrict__ w1 = (p == 0) ? w1t : ((p == 1) ? w1a : w1q);
  const float* __restrict__ b1 = (p == 0) ? b1t : ((p == 1) ? b1a : b1q);
  __shared__ float xs[2][32][32];   // [kgroup][kk][m]
  __shared__ float lsum[32][128];
  __shared__ int rid[32];
  const int t = threadIdx.x;
  if (t < 32) rid[t] = (t < nrows) ? rows[p * 64 + pref + rstart + t] : -1;
  const int kg = t >> 7, lc = t & 127;
  const int j = tile * 128 + lc;
  const float* __restrict__ wcol = w1 + (size_t)e * ND * NH + j;
  float acc[32];
#pragma unroll
  for (int m = 0; m < 32; ++m) acc[m] = 0.f;
  const int kbase = kg * 1152;
  const int sm = lc >> 2, skc = (lc & 3) * 8;
  __syncthreads();
  for (int k0 = 0; k0 < 1152; k0 += 32) {
    {
      int r = rid[sm];
#pragma unroll
      for (int i = 0; i < 2; ++i) {
        f32x4 v = {0.f, 0.f, 0.f, 0.f};
        if (r >= 0) v = *(const f32x4*)(xf + (size_t)r * ND + kbase + k0 + skc + i * 4);
        xs[kg][skc + i * 4 + 0][sm] = v[0];
        xs[kg][skc + i * 4 + 1][sm] = v[1];
        xs[kg][skc + i * 4 + 2][sm] = v[2];
        xs[kg][skc + i * 4 + 3][sm] = v[3];
      }
    }
    __syncthreads();
    const float* wp = wcol + (size_t)(kbase + k0) * NH;
#pragma unroll 4
    for (int kk = 0; kk < 32; ++kk) {
      float w = wp[(size_t)kk * NH];
      const f32x4* xrow = (const f32x4*)(&xs[kg][kk][0]);
#pragma unroll
      for (int mq = 0; mq < 8; ++mq) {
        f32x4 xv = xrow[mq];
        acc[mq * 4 + 0] = fmaf(xv[0], w, acc[mq * 4 + 0]);
        acc[mq * 4 + 1] = fmaf(xv[1], w, acc[mq * 4 + 1]);
        acc[mq * 4 + 2] = fmaf(xv[2], w, acc[mq * 4 + 2]);
        acc[mq * 4 + 3] = fmaf(xv[3], w, acc[mq * 4 + 3]);
      }
    }
    __syncthreads();
  }
  if (kg == 1) {
#pragma unroll
    for (int m = 0; m < 32; ++m) lsum[m][lc] = acc[m];
  }
  __syncthreads();
  if (kg == 0) {
    const float bias = b1[e * NH + j];
    float* hp = H + ((size_t)(p * 64 + pref + rstart)) * NH + j;
#pragma unroll
    for (int m = 0; m < 32; ++m) {
      if (m < nrows) hp[(size_t)m * NH] = fmaxf(acc[m] + lsum[m][lc] + bias, 0.f);
    }
  }
}

// MoE phase B: Y[p][b][j] = H @ w2[e] + b2[e], scattered back by sample id.
__global__ __launch_bounds__(256) void k_moe2(
    const float* __restrict__ H,
    const float* __restrict__ w2t, const float* __restrict__ w2a, const float* __restrict__ w2q,
    const float* __restrict__ b2t, const float* __restrict__ b2a, const float* __restrict__ b2q,
    const int* __restrict__ cnt, const int* __restrict__ rows, float* __restrict__ Y) {
  const int tile = blockIdx.x;                 // 18 tiles x 128 cols = 2304
  const int pe = blockIdx.y >> 1, g = blockIdx.y & 1;
  const int p = pe >> 2, e = pe & 3;
  const int c = cnt[p * 4 + e];
  const int rstart = g * 32;
  if (rstart >= c) return;
  const int nrows = min(32, c - rstart);
  int pref = 0;
  for (int e2 = 0; e2 < e; ++e2) pref += cnt[p * 4 + e2];
  const float* __restrict__ w2 = (p == 0) ? w2t : ((p == 1) ? w2a : w2q);
  const float* __restrict__ b2 = (p == 0) ? b2t : ((p == 1) ? b2a : b2q);
  __shared__ float xs[2][32][32];
  __shared__ float lsum[32][128];
  __shared__ int rid[32];
  const int t = threadIdx.x;
  if (t < 32) rid[t] = (t < nrows) ? rows[p * 64 + pref + rstart + t] : -1;
  const int kg = t >> 7, lc = t & 127;
  const int j = tile * 128 + lc;
  const float* __restrict__ wcol = w2 + (size_t)e * NH * ND + j;
  const float* __restrict__ hbase = H + ((size_t)(p * 64 + pref + rstart)) * NH;
  float acc[32];
#pragma unroll
  for (int m = 0; m < 32; ++m) acc[m] = 0.f;
  const int kbase = kg * 2304;
  const int sm = lc >> 2, skc = (lc & 3) * 8;
  __syncthreads();
  for (int k0 = 0; k0 < 2304; k0 += 32) {
    {
      const bool ok = (sm < nrows);
#pragma unroll
      for (int i = 0; i < 2; ++i) {
        f32x4 v = {0.f, 0.f, 0.f, 0.f};
        if (ok) v = *(const f32x4*)(hbase + (size_t)sm * NH + kbase + k0 + skc + i * 4);
        xs[kg][skc + i * 4 + 0][sm] = v[0];
        xs[kg][skc + i * 4 + 1][sm] = v[1];
        xs[kg][skc + i * 4 + 2][sm] = v[2];
        xs[kg][skc + i * 4 + 3][sm] = v[3];
      }
    }
    __syncthreads();
    const float* wp = wcol + (size_t)(kbase + k0) * ND;
#pragma unroll 4
    for (int kk = 0; kk < 32; ++kk) {
      float w = wp[(size_t)kk * ND];
      const f32x4* xrow = (const f32x4*)(&xs[kg][kk][0]);
#pragma unroll
      for (int mq = 0; mq < 8; ++mq) {
        f32x4 xv = xrow[mq];
        acc[mq * 4 + 0] = fmaf(xv[0], w, acc[mq * 4 + 0]);
        acc[mq * 4 + 1] = fmaf(xv[1], w, acc[mq * 4 + 1]);
        acc[mq * 4 + 2] = fmaf(xv[2], w, acc[mq * 4 + 2]);
        acc[mq * 4 + 3] = fmaf(xv[3], w, acc[mq * 4 + 3]);
      }
    }
    __syncthreads();
  }
  if (kg == 1) {
#pragma unroll
    for (int m = 0; m < 32; ++m) lsum[m][lc] = acc[m];
  }
  __syncthreads();
  if (kg == 0) {
    const float bias = b2[e * ND + j];
#pragma unroll
    for (int m = 0; m < 32; ++m) {
      if (m < nrows) Y[((size_t)(p * 64 + rid[m])) * ND + j] = acc[m] + lsum[m][lc] + bias;
    }
  }
}

// out = in*in*quad + in*transform + add, convert to bf16 for encoder GEMM.
__global__ __launch_bounds__(256) void k_combine(
    const float* __restrict__ in, const float* __restrict__ Y, u16* __restrict__ ofb) {
  const size_t i = (size_t)blockIdx.x * 256 + threadIdx.x;   // < 737280 float4s
  const size_t e0 = i * 4;
  const int row = (int)(e0 / ND);
  const int d = (int)(e0 - (size_t)row * ND);
  const int b = row / NL;
  f32x4 v = *(const f32x4*)(in + e0);
  const size_t yb = (size_t)b * ND + d;
  f32x4 tt = *(const f32x4*)(Y + yb);
  f32x4 aa = *(const f32x4*)(Y + (size_t)64 * ND + yb);
  f32x4 qq = *(const f32x4*)(Y + (size_t)128 * ND + yb);
  u16x4 o;
#pragma unroll
  for (int q = 0; q < 4; ++q) {
    float f = v[q] * v[q] * qq[q] + v[q] * tt[q] + aa[q];
    o[q] = f2bf(f);
  }
  *(u16x4*)(ofb + e0) = o;
}

// Transpose + fp32->bf16: W^T so GEMM B-operand is [N][K] row-major.
__global__ __launch_bounds__(256) void k_wt(
    const float* __restrict__ encw, const float* __restrict__ decw,
    u16* __restrict__ encb, u16* __restrict__ decb) {
  __shared__ float tl[32][33];
  const float* __restrict__ src = blockIdx.z ? decw : encw;
  u16* __restrict__ dst = blockIdx.z ? decb : encb;
  const int k0 = blockIdx.x * 32, n0 = blockIdx.y * 32;
  const int tx = threadIdx.x & 31, ty = threadIdx.x >> 5;
  for (int r = ty; r < 32; r += 8) tl[r][tx] = src[(size_t)(k0 + r) * ND + n0 + tx];
  __syncthreads();
  for (int r = ty; r < 32; r += 8) dst[(size_t)(n0 + r) * ND + k0 + tx] = f2bf(tl[tx][r]);
}

// 128x128 bf16 MFMA GEMM, A[M][K] row-major, Bt[N][K] row-major (pre-transposed).
// MODE 0: relu -> bf16 out. MODE 1: sigmoid -> f32 out + aux scalar.
template <int MODE>
__global__ __launch_bounds__(256) void k_gemm(
    const u16* __restrict__ A, const u16* __restrict__ Bt,
    const float* __restrict__ bias, void* __restrict__ outp,
    const float* __restrict__ aux) {
  __shared__ u16 As[128 * 32];
  __shared__ u16 Bs[128 * 32];
  const int t = threadIdx.x;
  const int bm = blockIdx.x, bn = blockIdx.y;
  const int lane = t & 63;
  const int wr = (t >> 7) & 1, wc = (t >> 6) & 1;
  const int l15 = lane & 15, l4 = lane >> 4;
  f32x4 acc[4][4] = {};
  const int r0 = t >> 2, kc0 = (t & 3) * 8;
  const int r1 = (t + 256) >> 2, kc1 = ((t + 256) & 3) * 8;
  const size_t baseA = (size_t)(bm * 128) * ND;
  const size_t baseB = (size_t)(bn * 128) * ND;
  for (int k0 = 0; k0 < ND; k0 += 32) {
    *(u32x4*)(As + t * 8) = *(const u32x4*)(A + baseA + (size_t)r0 * ND + k0 + kc0);
    *(u32x4*)(Bs + t * 8) = *(const u32x4*)(Bt + baseB + (size_t)r0 * ND + k0 + kc0);
    *(u32x4*)(As + (t + 256) * 8) = *(const u32x4*)(A + baseA + (size_t)r1 * ND + k0 + kc1);
    *(u32x4*)(Bs + (t + 256) * 8) = *(const u32x4*)(Bt + baseB + (size_t)r1 * ND + k0 + kc1);
    __syncthreads();
    bf16x8 af[4], bfr[4];
#pragma unroll
    for (int i = 0; i < 4; ++i) {
      af[i] = *(const bf16x8*)(As + (wr * 64 + i * 16 + l15) * 32 + l4 * 8);
      bfr[i] = *(const bf16x8*)(Bs + (wc * 64 + i * 16 + l15) * 32 + l4 * 8);
    }
#pragma unroll
    for (int mi = 0; mi < 4; ++mi)
#pragma unroll
      for (int ni = 0; ni < 4; ++ni)
        acc[mi][ni] = __builtin_amdgcn_mfma_f32_16x16x32_bf16(af[mi], bfr[ni], acc[mi][ni], 0, 0, 0);
    __syncthreads();
  }
  const int colbase = bn * 128 + wc * 64;
  const int rowbase = bm * 128 + wr * 64;
#pragma unroll
  for (int mi = 0; mi < 4; ++mi) {
#pragma unroll
    for (int ni = 0; ni < 4; ++ni) {
      const int colg = colbase + ni * 16 + l15;
      const float bv = bias[colg];
#pragma unroll
      for (int r = 0; r < 4; ++r) {
        const int rowg = rowbase + mi * 16 + l4 * 4 + r;
        float v = acc[mi][ni][r] + bv;
        if (MODE == 0) {
          ((u16*)outp)[(size_t)rowg * ND + colg] = f2bf(fmaxf(v, 0.f));
        } else {
          ((float*)outp)[(size_t)rowg * ND + colg] = 1.f / (1.f + __expf(-v));
        }
      }
    }
  }
  if (MODE == 1 && bm == 0 && bn == 0 && t == 0)
    ((float*)outp)[(size_t)NM * ND] = aux[0] + aux[1] + aux[2];
}

extern "C" void kernel_launch(void* const* d_in, const int* in_sizes, int n_in,
                              void* d_out, int out_size, void* d_ws, size_t ws_size,
                              hipStream_t stream) {
  (void)in_sizes; (void)n_in; (void)out_size; (void)ws_size;
  const float* input   = (const float*)d_in[0];
  const float* conv1_w = (const float*)d_in[1];
  const float* conv1_b = (const float*)d_in[2];
  const float* conv2_w = (const float*)d_in[3];
  const float* conv2_b = (const float*)d_in[4];
  const float* enc_w   = (const float*)d_in[5];
  const float* enc_b   = (const float*)d_in[6];
  const float* dec_w   = (const float*)d_in[7];
  const float* dec_b   = (const float*)d_in[8];
  const float* gate_t = (const float*)d_in[9];
  const float* w1_t   = (const float*)d_in[10];
  const float* b1_t   = (const float*)d_in[11];
  const float* w2_t   = (const float*)d_in[12];
  const float* b2_t   = (const float*)d_in[13];
  const float* gate_a = (const float*)d_in[14];
  const float* w1_a   = (const float*)d_in[15];
  const float* b1_a   = (const float*)d_in[16];
  const float* w2_a   = (const float*)d_in[17];
  const float* b2_a   = (const float*)d_in[18];
  const float* gate_q = (const float*)d_in[19];
  const float* w1_q   = (const float*)d_in[20];
  const float* b1_q   = (const float*)d_in[21];
  const float* w2_q   = (const float*)d_in[22];
  const float* b2_q   = (const float*)d_in[23];

  float* ws = (float*)d_ws;
  float* xf_acc = ws + OFF_XFACC;
  float* xf     = ws + OFF_XF;
  float* H      = ws + OFF_H;
  float* Y      = ws + OFF_Y;
  float* aux    = ws + OFF_AUX;
  int*   cnt    = (int*)(ws + OFF_CNT);
  int*   rows   = (int*)(ws + OFF_ROWS);
  u16*   ofb    = (u16*)(ws + OFF_OFB);
  u16*   h1b    = (u16*)(ws + OFF_H1B);
  u16*   encwb  = (u16*)(ws + OFF_ENCWB);
  u16*   decwb  = (u16*)(ws + OFF_DECWB);

  k_zero<<<576, 256, 0, stream>>>(xf_acc);
  k_conv<<<dim3(20, 64), 256, 0, stream>>>(input, conv1_w, conv1_b, conv2_w, xf_acc);
  k_bias_relu<<<576, 256, 0, stream>>>(xf_acc, conv2_b, xf);
  k_wt<<<dim3(72, 72, 2), 256, 0, stream>>>(enc_w, dec_w, encwb, decwb);
  k_gate<<<3, 256, 0, stream>>>(xf, gate_t, gate_a, gate_q, aux, cnt, rows);
  k_moe1<<<dim3(36, 24), 256, 0, stream>>>(xf, w1_t, w1_a, w1_q, b1_t, b1_a, b1_q, cnt, rows, H);
  k_moe2<<<dim3(18, 24), 256, 0, stream>>>(H, w2_t, w2_a, w2_q, b2_t, b2_a, b2_q, cnt, rows, Y);
  k_combine<<<2880, 256, 0, stream>>>(input, Y, ofb);
  k_gemm<0><<<dim3(10, 18), 256, 0, stream>>>(ofb, encwb, enc_b, (void*)h1b, aux);
  k_gemm<1><<<dim3(10, 18), 256, 0, stream>>>(h1b, decwb, dec_b, d_out, aux);
}

// Round 2
// 573.627 us; speedup vs baseline: 1.9499x; 1.9499x over previous
//
#include <hip/hip_runtime.h>
#include <stdint.h>

#define NB 64
#define NL 20
#define ND 2304
#define NE 4
#define NH 4608
#define NM 1280   // B*L

typedef float f32x4 __attribute__((ext_vector_type(4)));
typedef __bf16 bf16x8 __attribute__((ext_vector_type(8)));
typedef unsigned short u16;
typedef u16 u16x4 __attribute__((ext_vector_type(4)));
typedef unsigned int u32;
typedef u32 u32x4 __attribute__((ext_vector_type(4)));

__device__ __forceinline__ u16 f2bf(float f) {
  u32 u = __builtin_bit_cast(u32, f);
  u += 0x7fffu + ((u >> 16) & 1u);
  return (u16)(u >> 16);
}

// ---- ws layout (float offsets) ----
#define OFF_XFACC 0
#define OFF_XF    147456
#define OFF_H     294912     // [192][4608] f32
#define OFF_Y     1179648    // [192][2304] f32
#define OFF_AUX   1622016
#define OFF_CNT   1622020
#define OFF_ROWS  1622032
#define OFF_OFB   1622240
#define OFF_H1B   3096800
#define OFF_ENCWB 4571360
#define OFF_DECWB 7225568
#define OFF_XC    9879776    // [192][2304] f32 compacted xf
#define OFF_P     10322144   // partial buffer: max(8*192*4608, 16*192*2304) = 7077888 f32

__global__ __launch_bounds__(256) void k_zero(float* __restrict__ p) {
  p[(size_t)blockIdx.x * 256 + threadIdx.x] = 0.f;
}

// Fused conv1(3x3x3,pad1,relu) + conv2 d-slice partial, per (d,b) block.
__global__ __launch_bounds__(256) void k_conv(
    const float* __restrict__ in, const float* __restrict__ w1,
    const float* __restrict__ b1, const float* __restrict__ w2,
    float* __restrict__ xf_acc) {
  __shared__ float insl[3][50][50];
  __shared__ float c1[2][50][50];
  __shared__ float w1s[270];
  __shared__ float w2s[90];
  __shared__ float b1s[10];
  const int d = blockIdx.x, b = blockIdx.y, t = threadIdx.x;
  for (int i = t; i < 270; i += 256) w1s[i] = w1[i];
  for (int i = t; i < 90; i += 256) w2s[i] = w2[(size_t)((i / 9) * 20 + d) * 9 + (i % 9)];
  if (t < 10) b1s[t] = b1[t];
  for (int i = t; i < 7500; i += 256) {
    int s = i / 2500, rr = (i % 2500) / 50, cc = i % 50;
    int gd = d - 1 + s, gy = rr - 1, gx = cc - 1;
    float v = 0.f;
    if (gd >= 0 && gd < NL && (unsigned)gy < 48u && (unsigned)gx < 48u)
      v = in[((size_t)b * NL + gd) * ND + gy * 48 + gx];
    insl[s][rr][cc] = v;
  }
  for (int i = t; i < 5000; i += 256) ((float*)c1)[i] = 0.f;
  float s2[3][4];
#pragma unroll
  for (int qi = 0; qi < 3; ++qi)
#pragma unroll
    for (int xq = 0; xq < 4; ++xq) s2[qi][xq] = 0.f;
  __syncthreads();
  for (int pc = 0; pc < 5; ++pc) {
#pragma unroll
    for (int qi = 0; qi < 3; ++qi) {
      int q = t + qi * 256;
      if (q < 576) {
        int y = q / 12, x0 = (q % 12) * 4;
        float a0[4], a1[4];
        const float bb0 = b1s[2 * pc], bb1 = b1s[2 * pc + 1];
#pragma unroll
        for (int xq = 0; xq < 4; ++xq) { a0[xq] = bb0; a1[xq] = bb1; }
#pragma unroll
        for (int kd = 0; kd < 3; ++kd)
#pragma unroll
          for (int ky = 0; ky < 3; ++ky) {
            float v[6];
#pragma unroll
            for (int i = 0; i < 6; ++i) v[i] = insl[kd][y + ky][x0 + i];
            const float* wa = &w1s[(2 * pc) * 27 + kd * 9 + ky * 3];
            const float* wb = wa + 27;
#pragma unroll
            for (int xq = 0; xq < 4; ++xq) {
              a0[xq] += v[xq] * wa[0] + v[xq + 1] * wa[1] + v[xq + 2] * wa[2];
              a1[xq] += v[xq] * wb[0] + v[xq + 1] * wb[1] + v[xq + 2] * wb[2];
            }
          }
#pragma unroll
        for (int xq = 0; xq < 4; ++xq) {
          c1[0][y + 1][x0 + 1 + xq] = fmaxf(a0[xq], 0.f);
          c1[1][y + 1][x0 + 1 + xq] = fmaxf(a1[xq], 0.f);
        }
      }
    }
    __syncthreads();
#pragma unroll
    for (int qi = 0; qi < 3; ++qi) {
      int q = t + qi * 256;
      if (q < 576) {
        int y = q / 12, x0 = (q % 12) * 4;
#pragma unroll
        for (int cc = 0; cc < 2; ++cc) {
#pragma unroll
          for (int ky = 0; ky < 3; ++ky) {
            float v[6];
#pragma unroll
            for (int i = 0; i < 6; ++i) v[i] = c1[cc][y + ky][x0 + i];
            const float* wr = &w2s[(2 * pc + cc) * 9 + ky * 3];
#pragma unroll
            for (int xq = 0; xq < 4; ++xq)
              s2[qi][xq] += v[xq] * wr[0] + v[xq + 1] * wr[1] + v[xq + 2] * wr[2];
          }
        }
      }
    }
    __syncthreads();
  }
#pragma unroll
  for (int qi = 0; qi < 3; ++qi) {
    int q = t + qi * 256;
    if (q < 576) {
#pragma unroll
      for (int xq = 0; xq < 4; ++xq)
        atomicAdd(&xf_acc[(size_t)b * ND + q * 4 + xq], s2[qi][xq]);
    }
  }
}

__global__ __launch_bounds__(256) void k_bias_relu(
    const float* __restrict__ acc, const float* __restrict__ c2b, float* __restrict__ xf) {
  size_t i = (size_t)blockIdx.x * 256 + threadIdx.x;
  xf[i] = fmaxf(acc[i] + c2b[0], 0.f);
}

// Gating: logits, argmax (top-1, gate=1.0), counts, row compaction, aux loss.
__global__ __launch_bounds__(256) void k_gate(
    const float* __restrict__ xf,
    const float* __restrict__ g0, const float* __restrict__ g1, const float* __restrict__ g2,
    float* __restrict__ aux, int* __restrict__ cnt, int* __restrict__ rows) {
  const int p = blockIdx.x, t = threadIdx.x;
  const float* __restrict__ g = (p == 0) ? g0 : ((p == 1) ? g1 : g2);
  __shared__ float lg[64][4];
  __shared__ int lidx[64];
  __shared__ int lcnt[4];
  if (t < 4) lcnt[t] = 0;
  const int wv = t >> 6, l = t & 63;
  for (int b0 = 0; b0 < 64; b0 += 4) {
    int bb = b0 + wv;
    f32x4 acc = {0.f, 0.f, 0.f, 0.f};
    const float* xr = xf + (size_t)bb * ND + l * 36;
    const float* gr = g + (size_t)l * 36 * 4;
#pragma unroll
    for (int i4 = 0; i4 < 9; ++i4) {
      f32x4 xv = *(const f32x4*)(xr + i4 * 4);
#pragma unroll
      for (int qq = 0; qq < 4; ++qq) {
        f32x4 gv = *(const f32x4*)(gr + (i4 * 4 + qq) * 4);
        acc += xv[qq] * gv;
      }
    }
#pragma unroll
    for (int e = 0; e < 4; ++e) {
      float pv = acc[e];
#pragma unroll
      for (int off = 32; off > 0; off >>= 1) pv += __shfl_down(pv, off);
      if (l == 0) lg[bb][e] = pv;
    }
  }
  __syncthreads();
  if (t < 64) {
    float best = lg[t][0];
    int bi = 0;
#pragma unroll
    for (int e = 1; e < 4; ++e)
      if (lg[t][e] > best) { best = lg[t][e]; bi = e; }
    lidx[t] = bi;
    atomicAdd(&lcnt[bi], 1);
  }
  __syncthreads();
  if (t == 0) {
    int ofs[4]; int run = 0;
#pragma unroll
    for (int e = 0; e < 4; ++e) { ofs[e] = run; run += lcnt[e]; cnt[p * 4 + e] = lcnt[e]; }
    for (int b = 0; b < 64; ++b) { int e = lidx[b]; rows[p * 64 + ofs[e]++] = b; }
    float var = 0.f;
#pragma unroll
    for (int e = 0; e < 4; ++e) { float dd = (float)lcnt[e] - 16.f; var += dd * dd; }
    var *= (1.f / 3.f);
    aux[p] = 0.02f * var / (256.f + 1e-10f);
  }
}

// Compact xf rows into expert order: Xc[slot] = xf[rows[slot]].
__global__ __launch_bounds__(256) void k_gather(
    const float* __restrict__ xf, const int* __restrict__ rows, float* __restrict__ Xc) {
  const int slot = blockIdx.x, t = threadIdx.x;
  const int p = slot >> 6;
  const int r = rows[slot];
  const f32x4* src = (const f32x4*)(xf + ((size_t)(p * 0 + r)) * ND);  // xf row r (shared across p)
  f32x4* dst = (f32x4*)(Xc + (size_t)slot * ND);
  for (int i = t; i < ND / 4; i += 256) dst[i] = src[i];
}

// Weight-streaming partial-K expert GEMM.
// Grid: (N/128, KS, 24=3p*4e*2chunk). Block: 256 thr = 4 waves, each wave KL/4 k's.
// Per block: 32 rows (one chunk) x 128 cols x KL k-slice -> partial P[ks][slot][col].
template <int K, int N, int KS>
__global__ __launch_bounds__(256) void k_moe_stream(
    const float* __restrict__ Xc,
    const float* __restrict__ wt, const float* __restrict__ wa, const float* __restrict__ wq,
    const int* __restrict__ cnt, float* __restrict__ P) {
  constexpr int KL = K / KS;      // 288
  constexpr int KW = KL / 4;      // 72 per wave
  const int tile = blockIdx.x;
  const int ks = blockIdx.y;
  const int pe = blockIdx.z >> 1, ch = blockIdx.z & 1;
  const int p = pe >> 2, e = pe & 3;
  const int c = cnt[p * 4 + e];
  const int rstart = ch * 32;
  if (rstart >= c) return;
  const int nrows = min(32, c - rstart);
  int pref = 0;
  for (int e2 = 0; e2 < e; ++e2) pref += cnt[p * 4 + e2];
  const int slot0 = p * 64 + pref + rstart;
  const float* __restrict__ W = (p == 0) ? wt : ((p == 1) ? wa : wq);
  __shared__ float xs[32][KL + 4];
  const int t = threadIdx.x;
  // stage 32 rows x KL floats (f32x4, coalesced; clamped slots for tail rows)
  for (int i = t; i < 32 * (KL / 4); i += 256) {
    int r = i / (KL / 4), kq = (i - r * (KL / 4)) * 4;
    int slot = slot0 + r; if (slot > 191) slot = 191;
    *(f32x4*)(&xs[r][kq]) = *(const f32x4*)(Xc + (size_t)slot * K + ks * KL + kq);
  }
  __syncthreads();
  const int w = t >> 6, l = t & 63;
  const int j0 = tile * 128 + l * 2;
  const float* __restrict__ wp = W + (size_t)e * K * N + (size_t)(ks * KL + w * KW) * N + j0;
  const int kloc = w * KW;
  float acc0[32], acc1[32];
#pragma unroll
  for (int r = 0; r < 32; ++r) { acc0[r] = 0.f; acc1[r] = 0.f; }
  for (int kb = 0; kb < KW; kb += 4) {
    float2 wv0 = *(const float2*)(wp + (size_t)(kb + 0) * N);
    float2 wv1 = *(const float2*)(wp + (size_t)(kb + 1) * N);
    float2 wv2 = *(const float2*)(wp + (size_t)(kb + 2) * N);
    float2 wv3 = *(const float2*)(wp + (size_t)(kb + 3) * N);
#pragma unroll
    for (int rg = 0; rg < 8; ++rg) {
      if (rg * 4 < nrows) {   // wave-uniform skip of fully-dead 4-row groups
#pragma unroll
        for (int rr = 0; rr < 4; ++rr) {
          const int r = rg * 4 + rr;
          f32x4 xv = *(const f32x4*)(&xs[r][kloc + kb]);
          acc0[r] = fmaf(xv[0], wv0.x, acc0[r]);
          acc1[r] = fmaf(xv[0], wv0.y, acc1[r]);
          acc0[r] = fmaf(xv[1], wv1.x, acc0[r]);
          acc1[r] = fmaf(xv[1], wv1.y, acc1[r]);
          acc0[r] = fmaf(xv[2], wv2.x, acc0[r]);
          acc1[r] = fmaf(xv[2], wv2.y, acc1[r]);
          acc0[r] = fmaf(xv[3], wv3.x, acc0[r]);
          acc1[r] = fmaf(xv[3], wv3.y, acc1[r]);
        }
      }
    }
  }
  // cross-wave (4-way K) reduce via LDS overlay on xs, 4 batches of 8 rows
  float* red = &xs[0][0];
  const size_t pbase = (size_t)ks * 192 * N;
#pragma unroll
  for (int b = 0; b < 4; ++b) {
    __syncthreads();
#pragma unroll
    for (int rr = 0; rr < 8; ++rr) {
      const int r = b * 8 + rr;
      *(float2*)(&red[((w * 8 + rr) * 64 + l) * 2]) = make_float2(acc0[r], acc1[r]);
    }
    __syncthreads();
#pragma unroll
    for (int s = 0; s < 2; ++s) {
      const int rr = w * 2 + s;
      const int r = b * 8 + rr;
      if (r < nrows) {
        float2 s0 = *(const float2*)(&red[((0 * 8 + rr) * 64 + l) * 2]);
        float2 s1 = *(const float2*)(&red[((1 * 8 + rr) * 64 + l) * 2]);
        float2 s2 = *(const float2*)(&red[((2 * 8 + rr) * 64 + l) * 2]);
        float2 s3 = *(const float2*)(&red[((3 * 8 + rr) * 64 + l) * 2]);
        float2 o = make_float2(s0.x + s1.x + s2.x + s3.x, s0.y + s1.y + s2.y + s3.y);
        *(float2*)(P + pbase + (size_t)(slot0 + r) * N + j0) = o;
      }
    }
  }
}

// Reduce phase-A partials: H[slot][j] = relu(sum_ks P + b1[e]).
__global__ __launch_bounds__(256) void k_red1(
    const float* __restrict__ P,
    const float* __restrict__ b1t, const float* __restrict__ b1a, const float* __restrict__ b1q,
    const int* __restrict__ cnt, float* __restrict__ H) {
  const int slot = blockIdx.y;
  const int p = slot >> 6, pos = slot & 63;
  int e = 0, run = cnt[p * 4];
  while (pos >= run && e < 3) { ++e; run += cnt[p * 4 + e]; }
  const float* __restrict__ b1 = (p == 0) ? b1t : ((p == 1) ? b1a : b1q);
  const int j0 = blockIdx.x * 1024 + threadIdx.x * 4;
  if (j0 >= NH) return;
  f32x4 s = *(const f32x4*)(b1 + (size_t)e * NH + j0);
#pragma unroll
  for (int ks = 0; ks < 8; ++ks)
    s += *(const f32x4*)(P + ((size_t)ks * 192 + slot) * NH + j0);
  f32x4 r;
#pragma unroll
  for (int q = 0; q < 4; ++q) r[q] = fmaxf(s[q], 0.f);
  *(f32x4*)(H + (size_t)slot * NH + j0) = r;
}

// Reduce phase-B partials + scatter: Y[p*64+rows[slot]][j] = sum_ks P + b2[e].
__global__ __launch_bounds__(256) void k_red2(
    const float* __restrict__ P,
    const float* __restrict__ b2t, const float* __restrict__ b2a, const float* __restrict__ b2q,
    const int* __restrict__ cnt, const int* __restrict__ rows, float* __restrict__ Y) {
  const int slot = blockIdx.y;
  const int p = slot >> 6, pos = slot & 63;
  int e = 0, run = cnt[p * 4];
  while (pos >= run && e < 3) { ++e; run += cnt[p * 4 + e]; }
  const float* __restrict__ b2 = (p == 0) ? b2t : ((p == 1) ? b2a : b2q);
  const int b = rows[slot];
  const int t = threadIdx.x;
  if (t >= 192) return;
  const int j0 = blockIdx.x * 768 + t * 4;
  f32x4 s = *(const f32x4*)(b2 + (size_t)e * ND + j0);
#pragma unroll
  for (int ks = 0; ks < 16; ++ks)
    s += *(const f32x4*)(P + ((size_t)ks * 192 + slot) * ND + j0);
  *(f32x4*)(Y + (size_t)(p * 64 + b) * ND + j0) = s;
}

// out = in*in*quad + in*transform + add, convert to bf16 for encoder GEMM.
__global__ __launch_bounds__(256) void k_combine(
    const float* __restrict__ in, const float* __restrict__ Y, u16* __restrict__ ofb) {
  const size_t i = (size_t)blockIdx.x * 256 + threadIdx.x;
  const size_t e0 = i * 4;
  const int row = (int)(e0 / ND);
  const int d = (int)(e0 - (size_t)row * ND);
  const int b = row / NL;
  f32x4 v = *(const f32x4*)(in + e0);
  const size_t yb = (size_t)b * ND + d;
  f32x4 tt = *(const f32x4*)(Y + yb);
  f32x4 aa = *(const f32x4*)(Y + (size_t)64 * ND + yb);
  f32x4 qq = *(const f32x4*)(Y + (size_t)128 * ND + yb);
  u16x4 o;
#pragma unroll
  for (int q = 0; q < 4; ++q) {
    float f = v[q] * v[q] * qq[q] + v[q] * tt[q] + aa[q];
    o[q] = f2bf(f);
  }
  *(u16x4*)(ofb + e0) = o;
}

// Transpose + fp32->bf16: W^T so GEMM B-operand is [N][K] row-major.
__global__ __launch_bounds__(256) void k_wt(
    const float* __restrict__ encw, const float* __restrict__ decw,
    u16* __restrict__ encb, u16* __restrict__ decb) {
  __shared__ float tl[32][33];
  const float* __restrict__ src = blockIdx.z ? decw : encw;
  u16* __restrict__ dst = blockIdx.z ? decb : encb;
  const int k0 = blockIdx.x * 32, n0 = blockIdx.y * 32;
  const int tx = threadIdx.x & 31, ty = threadIdx.x >> 5;
  for (int r = ty; r < 32; r += 8) tl[r][tx] = src[(size_t)(k0 + r) * ND + n0 + tx];
  __syncthreads();
  for (int r = ty; r < 32; r += 8) dst[(size_t)(n0 + r) * ND + k0 + tx] = f2bf(tl[tx][r]);
}

// 128x128 bf16 MFMA GEMM, A[M][K] row-major, Bt[N][K] row-major (pre-transposed).
template <int MODE>
__global__ __launch_bounds__(256) void k_gemm(
    const u16* __restrict__ A, const u16* __restrict__ Bt,
    const float* __restrict__ bias, void* __restrict__ outp,
    const float* __restrict__ aux) {
  __shared__ u16 As[128 * 32];
  __shared__ u16 Bs[128 * 32];
  const int t = threadIdx.x;
  const int bm = blockIdx.x, bn = blockIdx.y;
  const int lane = t & 63;
  const int wr = (t >> 7) & 1, wc = (t >> 6) & 1;
  const int l15 = lane & 15, l4 = lane >> 4;
  f32x4 acc[4][4] = {};
  const int r0 = t >> 2, kc0 = (t & 3) * 8;
  const int r1 = (t + 256) >> 2, kc1 = ((t + 256) & 3) * 8;
  const size_t baseA = (size_t)(bm * 128) * ND;
  const size_t baseB = (size_t)(bn * 128) * ND;
  for (int k0 = 0; k0 < ND; k0 += 32) {
    *(u32x4*)(As + t * 8) = *(const u32x4*)(A + baseA + (size_t)r0 * ND + k0 + kc0);
    *(u32x4*)(Bs + t * 8) = *(const u32x4*)(Bt + baseB + (size_t)r0 * ND + k0 + kc0);
    *(u32x4*)(As + (t + 256) * 8) = *(const u32x4*)(A + baseA + (size_t)r1 * ND + k0 + kc1);
    *(u32x4*)(Bs + (t + 256) * 8) = *(const u32x4*)(Bt + baseB + (size_t)r1 * ND + k0 + kc1);
    __syncthreads();
    bf16x8 af[4], bfr[4];
#pragma unroll
    for (int i = 0; i < 4; ++i) {
      af[i] = *(const bf16x8*)(As + (wr * 64 + i * 16 + l15) * 32 + l4 * 8);
      bfr[i] = *(const bf16x8*)(Bs + (wc * 64 + i * 16 + l15) * 32 + l4 * 8);
    }
#pragma unroll
    for (int mi = 0; mi < 4; ++mi)
#pragma unroll
      for (int ni = 0; ni < 4; ++ni)
        acc[mi][ni] = __builtin_amdgcn_mfma_f32_16x16x32_bf16(af[mi], bfr[ni], acc[mi][ni], 0, 0, 0);
    __syncthreads();
  }
  const int colbase = bn * 128 + wc * 64;
  const int rowbase = bm * 128 + wr * 64;
#pragma unroll
  for (int mi = 0; mi < 4; ++mi) {
#pragma unroll
    for (int ni = 0; ni < 4; ++ni) {
      const int colg = colbase + ni * 16 + l15;
      const float bv = bias[colg];
#pragma unroll
      for (int r = 0; r < 4; ++r) {
        const int rowg = rowbase + mi * 16 + l4 * 4 + r;
        float v = acc[mi][ni][r] + bv;
        if (MODE == 0) {
          ((u16*)outp)[(size_t)rowg * ND + colg] = f2bf(fmaxf(v, 0.f));
        } else {
          ((float*)outp)[(size_t)rowg * ND + colg] = 1.f / (1.f + __expf(-v));
        }
      }
    }
  }
  if (MODE == 1 && bm == 0 && bn == 0 && t == 0)
    ((float*)outp)[(size_t)NM * ND] = aux[0] + aux[1] + aux[2];
}

extern "C" void kernel_launch(void* const* d_in, const int* in_sizes, int n_in,
                              void* d_out, int out_size, void* d_ws, size_t ws_size,
                              hipStream_t stream) {
  (void)in_sizes; (void)n_in; (void)out_size; (void)ws_size;
  const float* input   = (const float*)d_in[0];
  const float* conv1_w = (const float*)d_in[1];
  const float* conv1_b = (const float*)d_in[2];
  const float* conv2_w = (const float*)d_in[3];
  const float* conv2_b = (const float*)d_in[4];
  const float* enc_w   = (const float*)d_in[5];
  const float* enc_b   = (const float*)d_in[6];
  const float* dec_w   = (const float*)d_in[7];
  const float* dec_b   = (const float*)d_in[8];
  const float* gate_t = (const float*)d_in[9];
  const float* w1_t   = (const float*)d_in[10];
  const float* b1_t   = (const float*)d_in[11];
  const float* w2_t   = (const float*)d_in[12];
  const float* b2_t   = (const float*)d_in[13];
  const float* gate_a = (const float*)d_in[14];
  const float* w1_a   = (const float*)d_in[15];
  const float* b1_a   = (const float*)d_in[16];
  const float* w2_a   = (const float*)d_in[17];
  const float* b2_a   = (const float*)d_in[18];
  const float* gate_q = (const float*)d_in[19];
  const float* w1_q   = (const float*)d_in[20];
  const float* b1_q   = (const float*)d_in[21];
  const float* w2_q   = (const float*)d_in[22];
  const float* b2_q   = (const float*)d_in[23];

  float* ws = (float*)d_ws;
  float* xf_acc = ws + OFF_XFACC;
  float* xf     = ws + OFF_XF;
  float* H      = ws + OFF_H;
  float* Y      = ws + OFF_Y;
  float* aux    = ws + OFF_AUX;
  int*   cnt    = (int*)(ws + OFF_CNT);
  int*   rows   = (int*)(ws + OFF_ROWS);
  u16*   ofb    = (u16*)(ws + OFF_OFB);
  u16*   h1b    = (u16*)(ws + OFF_H1B);
  u16*   encwb  = (u16*)(ws + OFF_ENCWB);
  u16*   decwb  = (u16*)(ws + OFF_DECWB);
  float* Xc     = ws + OFF_XC;
  float* P      = ws + OFF_P;

  k_zero<<<576, 256, 0, stream>>>(xf_acc);
  k_conv<<<dim3(20, 64), 256, 0, stream>>>(input, conv1_w, conv1_b, conv2_w, xf_acc);
  k_bias_relu<<<576, 256, 0, stream>>>(xf_acc, conv2_b, xf);
  k_wt<<<dim3(72, 72, 2), 256, 0, stream>>>(enc_w, dec_w, encwb, decwb);
  k_gate<<<3, 256, 0, stream>>>(xf, gate_t, gate_a, gate_q, aux, cnt, rows);
  k_gather<<<192, 256, 0, stream>>>(xf, rows, Xc);
  // Phase A: [192][2304] @ w1 -> H [192][4608]
  k_moe_stream<ND, NH, 8><<<dim3(36, 8, 24), 256, 0, stream>>>(Xc, w1_t, w1_a, w1_q, cnt, P);
  k_red1<<<dim3(5, 192), 256, 0, stream>>>(P, b1_t, b1_a, b1_q, cnt, H);
  // Phase B: H @ w2 -> Y (scattered)
  k_moe_stream<NH, ND, 16><<<dim3(18, 16, 24), 256, 0, stream>>>(H, w2_t, w2_a, w2_q, cnt, P);
  k_red2<<<dim3(3, 192), 256, 0, stream>>>(P, b2_t, b2_a, b2_q, cnt, rows, Y);
  k_combine<<<2880, 256, 0, stream>>>(input, Y, ofb);
  k_gemm<0><<<dim3(10, 18), 256, 0, stream>>>(ofb, encwb, enc_b, (void*)h1b, aux);
  k_gemm<1><<<dim3(10, 18), 256, 0, stream>>>(h1b, decwb, dec_b, d_out, aux);
}